// Round 1
// baseline (178.206 us; speedup 1.0000x reference)
//
#include <hip/hip_runtime.h>
#include <hip/hip_bf16.h>

// LoRALinear: y = x @ W^T + b + (alpha/rank) * ((x @ A^T) @ B^T)
// Fold: W_eff = W + SCALING * (B @ A)  (1024x1024, bf16, in d_ws)
// Then single bf16-MFMA GEMM: y[M=32768][N=1024] = x[M][K=1024] @ W_eff^T + b

typedef __bf16 bf16;
typedef bf16 bf16x8 __attribute__((ext_vector_type(8)));
typedef float f32x4 __attribute__((ext_vector_type(4)));

constexpr int K_DIM = 1024;
constexpr int N_DIM = 1024;
constexpr float SCALING = 16.0f / 16.0f;

// ---------------- W_eff = W + SCALING * B@A, cast to bf16 ----------------
__global__ __launch_bounds__(256) void weff_kernel(
    const float* __restrict__ W, const float* __restrict__ A,
    const float* __restrict__ B, bf16* __restrict__ weff) {
  const int o = blockIdx.x;       // output row, 0..1023
  const int tid = threadIdx.x;
  float br[16];
#pragma unroll
  for (int r = 0; r < 16; ++r) br[r] = B[o * 16 + r];
#pragma unroll
  for (int j = 0; j < 4; ++j) {
    const int k = tid + j * 256;
    float s = W[o * K_DIM + k];
#pragma unroll
    for (int r = 0; r < 16; ++r) s += SCALING * br[r] * A[r * K_DIM + k];
    weff[o * K_DIM + k] = (bf16)s;
  }
}

// ---------------- GEMM: 128x128 tile, 4 waves, BK=32, 16x16x32 bf16 MFMA ----------------
// A (x) reg-staged fp32->bf16; B (W_eff) reg-staged bf16. Padded LDS stride 40
// elements (80 B = 5*16 B: b128-aligned, coprime bank-quad stride -> ~conflict-free).
constexpr int LDS_STRIDE = 40;

__global__ __launch_bounds__(256) void lora_gemm(
    const float* __restrict__ X, const bf16* __restrict__ Wf,
    const float* __restrict__ bias, float* __restrict__ Y) {
  __shared__ __align__(16) bf16 As[128 * LDS_STRIDE];
  __shared__ __align__(16) bf16 Bs[128 * LDS_STRIDE];

  const int tid = threadIdx.x;
  const int lane = tid & 63;
  const int wid = tid >> 6;
  const int wr = wid >> 1;   // wave row 0..1 (64 rows each)
  const int wc = wid & 1;    // wave col 0..1 (64 cols each)

  const int bid = blockIdx.x;
  const int bm = bid >> 3;   // 0..255
  const int bn = bid & 7;    // 0..7
  const long m0 = (long)bm * 128;
  const int n0 = bn * 128;

  // staging assignment: thread -> (row = tid>>1, k-half = tid&1), 16 elems each
  const int srow = tid >> 1;
  const int shalf = tid & 1;
  const float* xg = X + (m0 + srow) * K_DIM + shalf * 16;
  const bf16* wg = Wf + (n0 + srow) * K_DIM + shalf * 16;
  bf16* asw = &As[srow * LDS_STRIDE + shalf * 16];
  bf16* bsw = &Bs[srow * LDS_STRIDE + shalf * 16];

  // fragment read bases
  const int l15 = lane & 15;
  const int lq = lane >> 4;  // 0..3 -> k-offset lq*8
  const bf16* ara = &As[(wr * 64 + l15) * LDS_STRIDE + lq * 8];
  const bf16* brb = &Bs[(wc * 64 + l15) * LDS_STRIDE + lq * 8];

  f32x4 acc[4][4] = {};

  f32x4 av[4];
  bf16x8 bv[2];
  auto LOADS = [&](int kt) {
    const f32x4* xp = (const f32x4*)(xg + kt);
#pragma unroll
    for (int i = 0; i < 4; ++i) av[i] = xp[i];
    const bf16x8* wp = (const bf16x8*)(wg + kt);
    bv[0] = wp[0];
    bv[1] = wp[1];
  };

  LOADS(0);
  for (int kt = 0; kt < K_DIM; kt += 32) {
    __syncthreads();  // prior compute done reading LDS
    // convert fp32 x -> bf16, write 16 elems; write 16 bf16 of W_eff
    bf16x8 p0, p1;
#pragma unroll
    for (int j = 0; j < 4; ++j) {
      p0[j] = (bf16)av[0][j];
      p0[4 + j] = (bf16)av[1][j];
      p1[j] = (bf16)av[2][j];
      p1[4 + j] = (bf16)av[3][j];
    }
    *(bf16x8*)asw = p0;
    *(bf16x8*)(asw + 8) = p1;
    *(bf16x8*)bsw = bv[0];
    *(bf16x8*)(bsw + 8) = bv[1];
    __syncthreads();  // tile ready

    if (kt + 32 < K_DIM) LOADS(kt + 32);  // prefetch next tile into regs

    bf16x8 af[4], bfr[4];
#pragma unroll
    for (int mi = 0; mi < 4; ++mi)
      af[mi] = *(const bf16x8*)(ara + mi * 16 * LDS_STRIDE);
#pragma unroll
    for (int ni = 0; ni < 4; ++ni)
      bfr[ni] = *(const bf16x8*)(brb + ni * 16 * LDS_STRIDE);
#pragma unroll
    for (int mi = 0; mi < 4; ++mi)
#pragma unroll
      for (int ni = 0; ni < 4; ++ni)
        acc[mi][ni] = __builtin_amdgcn_mfma_f32_16x16x32_bf16(
            af[mi], bfr[ni], acc[mi][ni], 0, 0, 0);
  }

  // epilogue: D layout col = lane&15, row = (lane>>4)*4 + reg
  float bcol[4];
#pragma unroll
  for (int ni = 0; ni < 4; ++ni)
    bcol[ni] = bias[n0 + wc * 64 + ni * 16 + l15];
#pragma unroll
  for (int mi = 0; mi < 4; ++mi) {
#pragma unroll
    for (int ni = 0; ni < 4; ++ni) {
      const int col = n0 + wc * 64 + ni * 16 + l15;
#pragma unroll
      for (int i = 0; i < 4; ++i) {
        const long row = m0 + wr * 64 + mi * 16 + lq * 4 + i;
        Y[row * N_DIM + col] = acc[mi][ni][i] + bcol[ni];
      }
    }
  }
}

extern "C" void kernel_launch(void* const* d_in, const int* in_sizes, int n_in,
                              void* d_out, int out_size, void* d_ws, size_t ws_size,
                              hipStream_t stream) {
  const float* x = (const float*)d_in[0];
  const float* W = (const float*)d_in[1];
  const float* b = (const float*)d_in[2];
  const float* lA = (const float*)d_in[3];
  const float* lB = (const float*)d_in[4];
  float* y = (float*)d_out;
  bf16* weff = (bf16*)d_ws;  // needs 1024*1024*2 = 2 MB

  weff_kernel<<<dim3(1024), dim3(256), 0, stream>>>(W, lA, lB, weff);

  const int M = 8 * 4096;
  const int grid = (M / 128) * (N_DIM / 128);  // 256 * 8 = 2048
  lora_gemm<<<dim3(grid), dim3(256), 0, stream>>>(x, weff, b, y);
}

// Round 2
// 140.256 us; speedup vs baseline: 1.2706x; 1.2706x over previous
//
#include <hip/hip_runtime.h>
#include <hip/hip_bf16.h>
#include <stdint.h>

// LoRALinear: y = x @ W^T + b + (alpha/rank) * ((x @ A^T) @ B^T)
// Fold: W_eff = W + SCALING * (B @ A)  (1024x1024, bf16, ws[0..2MB))
// Pre-convert x fp32 -> bf16 into ws[2MB..66MB), then m97-structure GEMM:
//   global_load_lds(16B) both operands, XCD swizzle, XOR-chunk bank swizzle.

typedef __bf16 bf16;
typedef bf16 bf16x8 __attribute__((ext_vector_type(8)));
typedef float f32x4 __attribute__((ext_vector_type(4)));

constexpr int K_DIM = 1024;
constexpr int N_DIM = 1024;
constexpr int M_DIM = 8 * 4096;
constexpr float SCALING = 16.0f / 16.0f;

// ---------------- W_eff = W + SCALING * B@A, cast to bf16 ----------------
__global__ __launch_bounds__(256) void weff_kernel(
    const float* __restrict__ W, const float* __restrict__ A,
    const float* __restrict__ B, bf16* __restrict__ weff) {
  const int o = blockIdx.x;  // output row, 0..1023
  const int tid = threadIdx.x;
  float br[16];
#pragma unroll
  for (int r = 0; r < 16; ++r) br[r] = B[o * 16 + r];
#pragma unroll
  for (int j = 0; j < 4; ++j) {
    const int k = tid + j * 256;
    float s = W[o * K_DIM + k];
#pragma unroll
    for (int r = 0; r < 16; ++r) s += SCALING * br[r] * A[r * K_DIM + k];
    weff[o * K_DIM + k] = (bf16)s;
  }
}

// ---------------- x fp32 -> bf16 streaming convert ----------------
__global__ __launch_bounds__(256) void cvt_x(const float* __restrict__ X,
                                             bf16* __restrict__ Xb, long n) {
  const long stride = (long)gridDim.x * 256 * 8;
  for (long i = ((long)blockIdx.x * 256 + threadIdx.x) * 8; i < n; i += stride) {
    f32x4 a = *(const f32x4*)(X + i);
    f32x4 c = *(const f32x4*)(X + i + 4);
    bf16x8 o;
#pragma unroll
    for (int j = 0; j < 4; ++j) {
      o[j] = (bf16)a[j];
      o[4 + j] = (bf16)c[j];
    }
    *(bf16x8*)(Xb + i) = o;
  }
}

// ---------------- main GEMM: m97 structure ----------------
// 128x128 tile, 4 waves (2x2), BK=32, 16x16x32 bf16 MFMA, acc 4x4.
// LDS tiles [128 rows][32 bf16 = 64 B] linear; global source pre-permuted with
// chunk' = chunk ^ ((row>>1)&3) so swizzled fragment reads are conflict-free.

__device__ __forceinline__ void async16(const void* g, void* l) {
  __builtin_amdgcn_global_load_lds(
      (const __attribute__((address_space(1))) void*)g,
      (__attribute__((address_space(3))) void*)l, 16, 0, 0);
}

__global__ __launch_bounds__(256) void gemm_bt(
    const bf16* __restrict__ Xb, const bf16* __restrict__ Wf,
    const float* __restrict__ bias, float* __restrict__ Y) {
  __shared__ __align__(16) bf16 As[128 * 32];
  __shared__ __align__(16) bf16 Bs[128 * 32];

  const int tid = threadIdx.x;
  const int lane = tid & 63;
  const int wid = tid >> 6;
  const int wr = wid >> 1;  // 0..1
  const int wc = wid & 1;   // 0..1

  // XCD-aware bijective swizzle: 2048 % 8 == 0 -> wgid = (bid%8)*256 + bid/8
  const int bid = blockIdx.x;
  const int wgid = (bid & 7) * 256 + (bid >> 3);
  const int bm = wgid >> 3;  // 0..255
  const int bn = wgid & 7;   // 0..7
  const long m0 = (long)bm * 128;
  const int n0 = bn * 128;

  // staging: slot s = wid*64 + 256*i + lane (i=0,1); row = s>>2, chunk = s&3
  // global source chunk = (s&3) ^ ((row>>1)&3)   (inverse of read swizzle)
  const int l15 = lane & 15;
  const int lq = lane >> 4;  // 0..3

  const bf16* srcA[2];
  const bf16* srcB[2];
  bf16* ldsA[2];
  bf16* ldsB[2];
#pragma unroll
  for (int i = 0; i < 2; ++i) {
    const int srow = wid * 16 + i * 64 + (lane >> 2);
    const int gchunk = (lane & 3) ^ ((srow >> 1) & 3);
    srcA[i] = Xb + (m0 + srow) * K_DIM + gchunk * 8;
    srcB[i] = Wf + (long)(n0 + srow) * K_DIM + gchunk * 8;
    ldsA[i] = As + (wid * 64 + i * 256) * 8;  // wave-uniform, linear
    ldsB[i] = Bs + (wid * 64 + i * 256) * 8;
  }

  // fragment read swizzled chunk (same for all mi/ni: row base multiples of 16)
  const int kc = lq ^ ((l15 >> 1) & 3);

  f32x4 acc[4][4] = {};

  for (int kt = 0; kt < K_DIM; kt += 32) {
    __syncthreads();  // prior MFMA reads done, safe to overwrite LDS
    async16(srcA[0] + kt, ldsA[0]);
    async16(srcA[1] + kt, ldsA[1]);
    async16(srcB[0] + kt, ldsB[0]);
    async16(srcB[1] + kt, ldsB[1]);
    __syncthreads();  // drains vmcnt: tile ready

    bf16x8 af[4], bg[4];
#pragma unroll
    for (int mi = 0; mi < 4; ++mi)
      af[mi] = *(const bf16x8*)(As + (wr * 64 + mi * 16 + l15) * 32 + kc * 8);
#pragma unroll
    for (int ni = 0; ni < 4; ++ni)
      bg[ni] = *(const bf16x8*)(Bs + (wc * 64 + ni * 16 + l15) * 32 + kc * 8);
#pragma unroll
    for (int mi = 0; mi < 4; ++mi)
#pragma unroll
      for (int ni = 0; ni < 4; ++ni)
        acc[mi][ni] = __builtin_amdgcn_mfma_f32_16x16x32_bf16(
            af[mi], bg[ni], acc[mi][ni], 0, 0, 0);
  }

  // epilogue: D layout col = lane&15, row = (lane>>4)*4 + reg
  float bcol[4];
#pragma unroll
  for (int ni = 0; ni < 4; ++ni)
    bcol[ni] = bias[n0 + wc * 64 + ni * 16 + l15];
#pragma unroll
  for (int mi = 0; mi < 4; ++mi) {
#pragma unroll
    for (int ni = 0; ni < 4; ++ni) {
      const int col = n0 + wc * 64 + ni * 16 + l15;
#pragma unroll
      for (int i = 0; i < 4; ++i) {
        const long row = m0 + wr * 64 + mi * 16 + lq * 4 + i;
        Y[row * N_DIM + col] = acc[mi][ni][i] + bcol[ni];
      }
    }
  }
}

// ---------------- fallback (R0 kernel, fp32 reg-staged): used if ws too small ----------------
constexpr int LDS_STRIDE = 40;
__global__ __launch_bounds__(256) void lora_gemm_f32(
    const float* __restrict__ X, const bf16* __restrict__ Wf,
    const float* __restrict__ bias, float* __restrict__ Y) {
  __shared__ __align__(16) bf16 As[128 * LDS_STRIDE];
  __shared__ __align__(16) bf16 Bs[128 * LDS_STRIDE];
  const int tid = threadIdx.x;
  const int lane = tid & 63;
  const int wid = tid >> 6;
  const int wr = wid >> 1, wc = wid & 1;
  const int bid = blockIdx.x;
  const int bm = bid >> 3, bn = bid & 7;
  const long m0 = (long)bm * 128;
  const int n0 = bn * 128;
  const int srow = tid >> 1, shalf = tid & 1;
  const float* xg = X + (m0 + srow) * K_DIM + shalf * 16;
  const bf16* wg = Wf + (long)(n0 + srow) * K_DIM + shalf * 16;
  bf16* asw = &As[srow * LDS_STRIDE + shalf * 16];
  bf16* bsw = &Bs[srow * LDS_STRIDE + shalf * 16];
  const int l15 = lane & 15;
  const int lq = lane >> 4;
  const bf16* ara = &As[(wr * 64 + l15) * LDS_STRIDE + lq * 8];
  const bf16* brb = &Bs[(wc * 64 + l15) * LDS_STRIDE + lq * 8];
  f32x4 acc[4][4] = {};
  f32x4 av[4];
  bf16x8 bv[2];
  auto LOADS = [&](int kt) {
    const f32x4* xp = (const f32x4*)(xg + kt);
#pragma unroll
    for (int i = 0; i < 4; ++i) av[i] = xp[i];
    const bf16x8* wp = (const bf16x8*)(wg + kt);
    bv[0] = wp[0];
    bv[1] = wp[1];
  };
  LOADS(0);
  for (int kt = 0; kt < K_DIM; kt += 32) {
    __syncthreads();
    bf16x8 p0, p1;
#pragma unroll
    for (int j = 0; j < 4; ++j) {
      p0[j] = (bf16)av[0][j];
      p0[4 + j] = (bf16)av[1][j];
      p1[j] = (bf16)av[2][j];
      p1[4 + j] = (bf16)av[3][j];
    }
    *(bf16x8*)asw = p0;
    *(bf16x8*)(asw + 8) = p1;
    *(bf16x8*)bsw = bv[0];
    *(bf16x8*)(bsw + 8) = bv[1];
    __syncthreads();
    if (kt + 32 < K_DIM) LOADS(kt + 32);
    bf16x8 af[4], bfr[4];
#pragma unroll
    for (int mi = 0; mi < 4; ++mi)
      af[mi] = *(const bf16x8*)(ara + mi * 16 * LDS_STRIDE);
#pragma unroll
    for (int ni = 0; ni < 4; ++ni)
      bfr[ni] = *(const bf16x8*)(brb + ni * 16 * LDS_STRIDE);
#pragma unroll
    for (int mi = 0; mi < 4; ++mi)
#pragma unroll
      for (int ni = 0; ni < 4; ++ni)
        acc[mi][ni] = __builtin_amdgcn_mfma_f32_16x16x32_bf16(
            af[mi], bfr[ni], acc[mi][ni], 0, 0, 0);
  }
  float bcol[4];
#pragma unroll
  for (int ni = 0; ni < 4; ++ni)
    bcol[ni] = bias[n0 + wc * 64 + ni * 16 + l15];
#pragma unroll
  for (int mi = 0; mi < 4; ++mi)
#pragma unroll
    for (int ni = 0; ni < 4; ++ni) {
      const int col = n0 + wc * 64 + ni * 16 + l15;
#pragma unroll
      for (int i = 0; i < 4; ++i) {
        const long row = m0 + wr * 64 + mi * 16 + lq * 4 + i;
        Y[row * N_DIM + col] = acc[mi][ni][i] + bcol[ni];
      }
    }
}

extern "C" void kernel_launch(void* const* d_in, const int* in_sizes, int n_in,
                              void* d_out, int out_size, void* d_ws, size_t ws_size,
                              hipStream_t stream) {
  const float* x = (const float*)d_in[0];
  const float* W = (const float*)d_in[1];
  const float* b = (const float*)d_in[2];
  const float* lA = (const float*)d_in[3];
  const float* lB = (const float*)d_in[4];
  float* y = (float*)d_out;

  bf16* weff = (bf16*)d_ws;  // 2 MB
  const size_t weff_bytes = (size_t)N_DIM * K_DIM * sizeof(bf16);
  const size_t xb_bytes = (size_t)M_DIM * K_DIM * sizeof(bf16);

  weff_kernel<<<dim3(1024), dim3(256), 0, stream>>>(W, lA, lB, weff);

  const int grid = (M_DIM / 128) * (N_DIM / 128);  // 2048

  if (ws_size >= weff_bytes + xb_bytes) {
    bf16* xb = (bf16*)((char*)d_ws + weff_bytes);
    cvt_x<<<dim3(2048), dim3(256), 0, stream>>>(x, xb, (long)M_DIM * K_DIM);
    gemm_bt<<<dim3(grid), dim3(256), 0, stream>>>(xb, weff, b, y);
  } else {
    lora_gemm_f32<<<dim3(grid), dim3(256), 0, stream>>>(x, weff, b, y);
  }
}

// Round 3
// 125.679 us; speedup vs baseline: 1.4179x; 1.1160x over previous
//
#include <hip/hip_runtime.h>
#include <hip/hip_bf16.h>

// LoRALinear: y = x @ W^T + b + 1.0 * ((x @ A^T) @ B^T)
// W_eff = W + B@A (bf16, ws[0..2MB)); x -> bf16 (ws[2MB..69MB));
// then 256x256x64 8-phase counted-vmcnt GEMM (T1+T2+T3+T4+T5).

typedef __bf16 bf16;
typedef bf16 bf16x8 __attribute__((ext_vector_type(8)));
typedef float f32x4 __attribute__((ext_vector_type(4)));

constexpr int K_DIM = 1024;
constexpr int N_DIM = 1024;
constexpr int M_DIM = 8 * 4096;
constexpr int NT = K_DIM / 64;  // 16 K-tiles
constexpr float SCALING = 16.0f / 16.0f;

// ---------------- W_eff = W + B@A, cast to bf16 ----------------
__global__ __launch_bounds__(256) void weff_kernel(
    const float* __restrict__ W, const float* __restrict__ A,
    const float* __restrict__ B, bf16* __restrict__ weff) {
  const int o = blockIdx.x;
  const int tid = threadIdx.x;
  float br[16];
#pragma unroll
  for (int r = 0; r < 16; ++r) br[r] = B[o * 16 + r];
#pragma unroll
  for (int j = 0; j < 4; ++j) {
    const int k = tid + j * 256;
    float s = W[o * K_DIM + k];
#pragma unroll
    for (int r = 0; r < 16; ++r) s += SCALING * br[r] * A[r * K_DIM + k];
    weff[o * K_DIM + k] = (bf16)s;
  }
}

// ---------------- x fp32 -> bf16 streaming convert ----------------
__global__ __launch_bounds__(256) void cvt_x(const float* __restrict__ X,
                                             bf16* __restrict__ Xb, long n) {
  const long stride = (long)gridDim.x * 256 * 8;
  for (long i = ((long)blockIdx.x * 256 + threadIdx.x) * 8; i < n; i += stride) {
    f32x4 a = *(const f32x4*)(X + i);
    f32x4 c = *(const f32x4*)(X + i + 4);
    bf16x8 o;
#pragma unroll
    for (int j = 0; j < 4; ++j) {
      o[j] = (bf16)a[j];
      o[4 + j] = (bf16)c[j];
    }
    *(bf16x8*)(Xb + i) = o;
  }
}

// ---------------- 8-phase 256x256 GEMM ----------------
__device__ __forceinline__ void async16(const void* g, void* l) {
  __builtin_amdgcn_global_load_lds(
      (const __attribute__((address_space(1))) void*)g,
      (__attribute__((address_space(3))) void*)l, 16, 0, 0);
}
#define BAR() __builtin_amdgcn_s_barrier()
#define LGKM0()                                        \
  do {                                                 \
    asm volatile("s_waitcnt lgkmcnt(0)" ::: "memory"); \
    __builtin_amdgcn_sched_barrier(0);                 \
  } while (0)
#define VMW(n) asm volatile("s_waitcnt vmcnt(" #n ")" ::: "memory")
#define MFMA(d, a, b) d = __builtin_amdgcn_mfma_f32_16x16x32_bf16(a, b, d, 0, 0, 0)

// LDS map (elements, bf16): buf c at c*32768; A region [0,16384), B [16384,32768).
// Row = 64 bf16 = 128 B = 8 chunks of 16 B; stored chunk c holds global chunk
// c ^ (row & 7)  (both-sides swizzle: pre-permuted global source, XORed read).

__global__ __launch_bounds__(512, 2) void gemm8(
    const bf16* __restrict__ Xb, const bf16* __restrict__ Wf,
    const float* __restrict__ bias, float* __restrict__ Y) {
  __shared__ __align__(16) bf16 smem[65536];  // 128 KiB

  const int tid = threadIdx.x;
  const int lane = tid & 63;
  const int wid = tid >> 6;
  const int wm = wid >> 2;  // 0..1  (A half)
  const int wn = wid & 3;   // 0..3  (B quarter)
  const int l15 = lane & 15;
  const int lq = lane >> 4;

  // XCD-aware bijective swizzle (512 % 8 == 0)
  const int bid = blockIdx.x;
  const int wgid = (bid & 7) * 64 + (bid >> 3);
  const int bm = wgid >> 2;  // 0..127
  const int bn = wgid & 3;   // 0..3
  const long m0 = (long)bm * 256;
  const int n0 = bn * 256;

  // staging: thread covers chunks s = j*512+tid (j=0,1); row=s>>3, chunk=s&7
  const int srow = tid >> 3;                  // 0..63
  const int gch = (tid & 7) ^ (srow & 7);     // same for j=0,1 (64 = 0 mod 8)
  const bf16* xsrc = Xb + (m0 + srow) * K_DIM + gch * 8;
  const bf16* wsrc = Wf + (long)(n0 + srow) * K_DIM + gch * 8;

  auto stageA = [&](int tt, int h) {
    bf16* dst = smem + (tt & 1) * 32768 + h * 8192 + tid * 8;
    const bf16* s = xsrc + (long)h * 128 * K_DIM + tt * 64;
    async16(s, dst);
    async16(s + 64 * K_DIM, dst + 4096);
  };
  auto stageB = [&](int tt, int h) {
    bf16* dst = smem + (tt & 1) * 32768 + 16384 + h * 8192 + tid * 8;
    const bf16* s = wsrc + (long)h * 128 * K_DIM + tt * 64;
    async16(s, dst);
    async16(s + 64 * K_DIM, dst + 4096);
  };

  // fragment read element-offsets; kk=1 toggles element bit 5 (chunk^4)
  const int key = l15 & 7;
  const int ck0 = lq ^ key;
  const int eA = (wm * 128 + l15) * 64 + ck0 * 8;
  const int eB = (wn * 64 + l15) * 64 + ck0 * 8;

  f32x4 acc[8][4] = {};

  // prologue: tiles 0 and 1 fully staged; allow tile1 (8 loads) in flight
  stageA(0, 0); stageA(0, 1); stageB(0, 0); stageB(0, 1);
  stageA(1, 0); stageA(1, 1); stageB(1, 0); stageB(1, 1);
  VMW(8);
  BAR();

  for (int t = 0; t < NT; ++t) {
    const bf16* Ab = smem + (t & 1) * 32768;
    const bf16* Bb = Ab + 16384;
    bf16x8 B0[4], B1[4];
    {  // p1: (mi0-3, kk0) x (ni0-3, kk0)
      bf16x8 A[4];
#pragma unroll
      for (int i = 0; i < 4; ++i) A[i] = *(const bf16x8*)(Ab + eA + i * 1024);
#pragma unroll
      for (int i = 0; i < 4; ++i) B0[i] = *(const bf16x8*)(Bb + eB + i * 1024);
      if (t >= 1 && t < NT - 1) stageA(t + 1, 0);
      BAR();
      LGKM0();
      __builtin_amdgcn_s_setprio(1);
#pragma unroll
      for (int m = 0; m < 4; ++m)
#pragma unroll
        for (int n = 0; n < 4; ++n) MFMA(acc[m][n], A[m], B0[n]);
      __builtin_amdgcn_s_setprio(0);
      BAR();
    }
    {  // p2: (mi0-3, kk1)
      bf16x8 A[4];
#pragma unroll
      for (int i = 0; i < 4; ++i)
        A[i] = *(const bf16x8*)(Ab + (eA ^ 32) + i * 1024);
#pragma unroll
      for (int i = 0; i < 4; ++i)
        B1[i] = *(const bf16x8*)(Bb + (eB ^ 32) + i * 1024);
      if (t >= 1 && t < NT - 1) stageA(t + 1, 1);
      BAR();
      LGKM0();
      __builtin_amdgcn_s_setprio(1);
#pragma unroll
      for (int m = 0; m < 4; ++m)
#pragma unroll
        for (int n = 0; n < 4; ++n) MFMA(acc[m][n], A[m], B1[n]);
      __builtin_amdgcn_s_setprio(0);
      BAR();
    }
    {  // p3: (mi4-7, kk0) — B region of THIS buf now dead -> stage B(t+2)lo
      bf16x8 A[4];
#pragma unroll
      for (int i = 0; i < 4; ++i)
        A[i] = *(const bf16x8*)(Ab + eA + 4096 + i * 1024);
      if (t < NT - 2) stageB(t + 2, 0);
      BAR();
      LGKM0();
      __builtin_amdgcn_s_setprio(1);
#pragma unroll
      for (int m = 0; m < 4; ++m)
#pragma unroll
        for (int n = 0; n < 4; ++n) MFMA(acc[4 + m][n], A[m], B0[n]);
      __builtin_amdgcn_s_setprio(0);
      BAR();
    }
    {  // p4: (mi4-7, kk1) + stage B(t+2)hi + boundary vmcnt
      bf16x8 A[4];
#pragma unroll
      for (int i = 0; i < 4; ++i)
        A[i] = *(const bf16x8*)(Ab + (eA ^ 32) + 4096 + i * 1024);
      if (t < NT - 2) stageB(t + 2, 1);
      BAR();
      LGKM0();
      __builtin_amdgcn_s_setprio(1);
#pragma unroll
      for (int m = 0; m < 4; ++m)
#pragma unroll
        for (int n = 0; n < 4; ++n) MFMA(acc[4 + m][n], A[m], B1[n]);
      __builtin_amdgcn_s_setprio(0);
      // boundary: next tile needs A(t+1),B(t+1) retired; B(t+2) may stay in flight
      if (t < NT - 2) {
        VMW(4);
      } else if (t == NT - 2) {
        VMW(0);
      }
      BAR();
    }
  }

  // epilogue: C/D layout col = lane&15, row = lq*4 + reg
  const long crow0 = m0 + wm * 128 + lq * 4;
  const int ccol0 = n0 + wn * 64 + l15;
  float bn4[4];
#pragma unroll
  for (int n = 0; n < 4; ++n) bn4[n] = bias[ccol0 + n * 16];
#pragma unroll
  for (int m = 0; m < 8; ++m)
#pragma unroll
    for (int n = 0; n < 4; ++n) {
      const int col = ccol0 + n * 16;
#pragma unroll
      for (int i = 0; i < 4; ++i)
        Y[(crow0 + m * 16 + i) * N_DIM + col] = acc[m][n][i] + bn4[n];
    }
}

extern "C" void kernel_launch(void* const* d_in, const int* in_sizes, int n_in,
                              void* d_out, int out_size, void* d_ws, size_t ws_size,
                              hipStream_t stream) {
  const float* x = (const float*)d_in[0];
  const float* W = (const float*)d_in[1];
  const float* b = (const float*)d_in[2];
  const float* lA = (const float*)d_in[3];
  const float* lB = (const float*)d_in[4];
  float* y = (float*)d_out;

  bf16* weff = (bf16*)d_ws;
  const size_t weff_bytes = (size_t)N_DIM * K_DIM * sizeof(bf16);
  bf16* xb = (bf16*)((char*)d_ws + weff_bytes);

  weff_kernel<<<dim3(1024), dim3(256), 0, stream>>>(W, lA, lB, weff);
  cvt_x<<<dim3(2048), dim3(256), 0, stream>>>(x, xb, (long)M_DIM * K_DIM);

  const int grid = (M_DIM / 256) * (N_DIM / 256);  // 128 * 4 = 512
  gemm8<<<dim3(grid), dim3(512), 0, stream>>>(xb, weff, b, y);
}

// Round 4
// 119.731 us; speedup vs baseline: 1.4884x; 1.0497x over previous
//
#include <hip/hip_runtime.h>
#include <hip/hip_bf16.h>

// LoRALinear: y = x @ W^T + b + 1.0 * ((x @ A^T) @ B^T)
// W_eff = W + B@A (bf16, ws[0..2MB)).
// Single fused GEMM: 256x256x64 8-phase counted-vmcnt (T1+T2+T3+T4+T5),
// A (x fp32) reg-staged with fused fp32->bf16 conversion (T14 split:
// loads issued p1/p2, cvt+ds_write p3/p4); B via global_load_lds.

typedef __bf16 bf16;
typedef bf16 bf16x8 __attribute__((ext_vector_type(8)));
typedef float f32x4 __attribute__((ext_vector_type(4)));

constexpr int K_DIM = 1024;
constexpr int N_DIM = 1024;
constexpr int M_DIM = 8 * 4096;
constexpr int NT = K_DIM / 64;  // 16 K-tiles
constexpr float SCALING = 16.0f / 16.0f;

// ---------------- W_eff = W + B@A, cast to bf16 ----------------
__global__ __launch_bounds__(256) void weff_kernel(
    const float* __restrict__ W, const float* __restrict__ A,
    const float* __restrict__ B, bf16* __restrict__ weff) {
  const int o = blockIdx.x;
  const int tid = threadIdx.x;
  float br[16];
#pragma unroll
  for (int r = 0; r < 16; ++r) br[r] = B[o * 16 + r];
#pragma unroll
  for (int j = 0; j < 4; ++j) {
    const int k = tid + j * 256;
    float s = W[o * K_DIM + k];
#pragma unroll
    for (int r = 0; r < 16; ++r) s += SCALING * br[r] * A[r * K_DIM + k];
    weff[o * K_DIM + k] = (bf16)s;
  }
}

// ---------------- fused 8-phase 256x256 GEMM ----------------
__device__ __forceinline__ void async16(const void* g, void* l) {
  __builtin_amdgcn_global_load_lds(
      (const __attribute__((address_space(1))) void*)g,
      (__attribute__((address_space(3))) void*)l, 16, 0, 0);
}
#define BAR() __builtin_amdgcn_s_barrier()
#define LGKM0()                                        \
  do {                                                 \
    asm volatile("s_waitcnt lgkmcnt(0)" ::: "memory"); \
    __builtin_amdgcn_sched_barrier(0);                 \
  } while (0)
#define VMW(n) asm volatile("s_waitcnt vmcnt(" #n ")" ::: "memory")
#define MFMA(d, a, b) d = __builtin_amdgcn_mfma_f32_16x16x32_bf16(a, b, d, 0, 0, 0)

// LDS (bf16 elems): buf c at c*32768; A [0,16384), B [16384,32768).
// Row = 64 bf16 = 8 chunks of 16 B; stored chunk s holds global chunk s^(row&7).

__global__ __launch_bounds__(512, 2) void gemm8f(
    const float* __restrict__ Xf, const bf16* __restrict__ Wf,
    const float* __restrict__ bias, float* __restrict__ Y) {
  __shared__ __align__(16) bf16 smem[65536];  // 128 KiB

  const int tid = threadIdx.x;
  const int lane = tid & 63;
  const int wid = tid >> 6;
  const int wm = wid >> 2;  // 0..1
  const int wn = wid & 3;   // 0..3
  const int l15 = lane & 15;
  const int lq = lane >> 4;

  // XCD-aware bijective swizzle (512 % 8 == 0); bn fastest -> same-bm blocks
  // are consecutive wgids -> same XCD -> x-slab L2 reuse.
  const int bid = blockIdx.x;
  const int wgid = (bid & 7) * 64 + (bid >> 3);
  const int bm = wgid >> 2;  // 0..127
  const int bn = wgid & 3;   // 0..3
  const long m0 = (long)bm * 256;
  const int n0 = bn * 256;

  // ---- B staging (global_load_lds, pre-swizzled source) ----
  const int srow = tid >> 3;               // 0..63
  const int gch = (tid & 7) ^ (srow & 7);  // inverse of read swizzle
  const bf16* wsrc = Wf + (long)(n0 + srow) * K_DIM + gch * 8;
  auto stageB = [&](int tt, int h) {
    bf16* dst = smem + (tt & 1) * 32768 + 16384 + h * 8192 + tid * 8;
    const bf16* s = wsrc + (long)h * 128 * K_DIM + tt * 64;
    async16(s, dst);
    async16(s + 64 * K_DIM, dst + 4096);
  };

  // ---- A staging (reg-staged fp32 -> bf16, swizzled ds_write) ----
  const int arow = tid >> 2;  // 0..127 (row within 128-row half)
  const int acp = tid & 3;    // chunk pair: global chunks 2acp, 2acp+1
  const int ar7 = arow & 7;
  const int aslot0 = (2 * acp) ^ ar7;      // stored slot holding gchunk 2acp
  const int aslot1 = (2 * acp + 1) ^ ar7;  // stored slot holding gchunk 2acp+1
  const float* asrc = Xf + (m0 + arow) * K_DIM + acp * 16;

  f32x4 rA0[4], rA1[4];  // in-flight A data for halves 0/1
  auto loadA0 = [&](int tt) {
    const float* s = asrc + tt * 64;
#pragma unroll
    for (int i = 0; i < 4; ++i) rA0[i] = *(const f32x4*)(s + i * 4);
  };
  auto loadA1 = [&](int tt) {
    const float* s = asrc + (long)128 * K_DIM + tt * 64;
#pragma unroll
    for (int i = 0; i < 4; ++i) rA1[i] = *(const f32x4*)(s + i * 4);
  };
  auto writeA = [&](int tt, int h, f32x4* r) {
    bf16* dst = smem + (tt & 1) * 32768 + h * 8192 + arow * 64;
    bf16x8 c0, c1;
#pragma unroll
    for (int j = 0; j < 4; ++j) {
      c0[j] = (bf16)r[0][j];
      c0[4 + j] = (bf16)r[1][j];
      c1[j] = (bf16)r[2][j];
      c1[4 + j] = (bf16)r[3][j];
    }
    *(bf16x8*)(dst + aslot0 * 8) = c0;
    *(bf16x8*)(dst + aslot1 * 8) = c1;
  };

  // fragment read offsets (XOR bank swizzle); kk=1 -> elem offset ^32
  const int key = l15 & 7;
  const int ck0 = lq ^ key;
  const int eA = (wm * 128 + l15) * 64 + ck0 * 8;
  const int eB = (wn * 64 + l15) * 64 + ck0 * 8;

  f32x4 acc[8][4] = {};

  // ---- prologue: B(0),B(1) async; A(0),A(1) via regs ----
  stageB(0, 0); stageB(0, 1); stageB(1, 0); stageB(1, 1);
  loadA0(0); loadA1(0);
  writeA(0, 0, rA0); writeA(0, 1, rA1);
  loadA0(1); loadA1(1);
  writeA(1, 0, rA0); writeA(1, 1, rA1);
  VMW(0);
  asm volatile("s_waitcnt lgkmcnt(0)" ::: "memory");
  BAR();

  for (int t = 0; t < NT; ++t) {
    const bf16* Ab = smem + (t & 1) * 32768;
    const bf16* Bb = Ab + 16384;
    bf16x8 B0[4], B1[4];
    {  // p1: (m0-3, kk0); issue A(t+1) h0 loads
      bf16x8 A[4];
#pragma unroll
      for (int i = 0; i < 4; ++i) A[i] = *(const bf16x8*)(Ab + eA + i * 1024);
#pragma unroll
      for (int i = 0; i < 4; ++i) B0[i] = *(const bf16x8*)(Bb + eB + i * 1024);
      if (t < NT - 1) loadA0(t + 1);
      BAR();
      LGKM0();
      __builtin_amdgcn_s_setprio(1);
#pragma unroll
      for (int m = 0; m < 4; ++m)
#pragma unroll
        for (int n = 0; n < 4; ++n) MFMA(acc[m][n], A[m], B0[n]);
      __builtin_amdgcn_s_setprio(0);
      BAR();
    }
    {  // p2: (m0-3, kk1); issue A(t+1) h1 loads
      bf16x8 A[4];
#pragma unroll
      for (int i = 0; i < 4; ++i)
        A[i] = *(const bf16x8*)(Ab + (eA ^ 32) + i * 1024);
#pragma unroll
      for (int i = 0; i < 4; ++i)
        B1[i] = *(const bf16x8*)(Bb + (eB ^ 32) + i * 1024);
      if (t < NT - 1) loadA1(t + 1);
      BAR();
      LGKM0();
      __builtin_amdgcn_s_setprio(1);
#pragma unroll
      for (int m = 0; m < 4; ++m)
#pragma unroll
        for (int n = 0; n < 4; ++n) MFMA(acc[m][n], A[m], B1[n]);
      __builtin_amdgcn_s_setprio(0);
      BAR();
    }
    {  // p3: (m4-7, kk0); stage B(t+2) lo into dead region; write A(t+1) h0
      bf16x8 A[4];
#pragma unroll
      for (int i = 0; i < 4; ++i)
        A[i] = *(const bf16x8*)(Ab + eA + 4096 + i * 1024);
      if (t < NT - 2) stageB(t + 2, 0);
      if (t < NT - 1) writeA(t + 1, 0, rA0);
      BAR();
      LGKM0();
      __builtin_amdgcn_s_setprio(1);
#pragma unroll
      for (int m = 0; m < 4; ++m)
#pragma unroll
        for (int n = 0; n < 4; ++n) MFMA(acc[4 + m][n], A[m], B0[n]);
      __builtin_amdgcn_s_setprio(0);
      BAR();
    }
    {  // p4: (m4-7, kk1); stage B(t+2) hi; write A(t+1) h1; counted boundary
      bf16x8 A[4];
#pragma unroll
      for (int i = 0; i < 4; ++i)
        A[i] = *(const bf16x8*)(Ab + (eA ^ 32) + 4096 + i * 1024);
      if (t < NT - 2) stageB(t + 2, 1);
      if (t < NT - 1) writeA(t + 1, 1, rA1);
      BAR();
      LGKM0();
      __builtin_amdgcn_s_setprio(1);
#pragma unroll
      for (int m = 0; m < 4; ++m)
#pragma unroll
        for (int n = 0; n < 4; ++n) MFMA(acc[4 + m][n], A[m], B1[n]);
      __builtin_amdgcn_s_setprio(0);
      if (t < NT - 2) {
        VMW(4);  // allow B(t+2)'s 4 loads across the boundary; B(t+1) retired
      } else {
        VMW(0);  // drain at tail (nearly free: nothing else outstanding)
      }
      BAR();
    }
  }

  // epilogue: C/D layout col = lane&15, row = lq*4 + reg
  const long crow0 = m0 + wm * 128 + lq * 4;
  const int ccol0 = n0 + wn * 64 + l15;
  float bn4[4];
#pragma unroll
  for (int n = 0; n < 4; ++n) bn4[n] = bias[ccol0 + n * 16];
#pragma unroll
  for (int m = 0; m < 8; ++m)
#pragma unroll
    for (int n = 0; n < 4; ++n) {
      const int col = ccol0 + n * 16;
#pragma unroll
      for (int i = 0; i < 4; ++i)
        Y[(crow0 + m * 16 + i) * N_DIM + col] = acc[m][n][i] + bn4[n];
    }
}

extern "C" void kernel_launch(void* const* d_in, const int* in_sizes, int n_in,
                              void* d_out, int out_size, void* d_ws, size_t ws_size,
                              hipStream_t stream) {
  const float* x = (const float*)d_in[0];
  const float* W = (const float*)d_in[1];
  const float* b = (const float*)d_in[2];
  const float* lA = (const float*)d_in[3];
  const float* lB = (const float*)d_in[4];
  float* y = (float*)d_out;

  bf16* weff = (bf16*)d_ws;  // 2 MB

  weff_kernel<<<dim3(1024), dim3(256), 0, stream>>>(W, lA, lB, weff);

  const int grid = (M_DIM / 256) * (N_DIM / 256);  // 128 * 4 = 512
  gemm8f<<<dim3(grid), dim3(512), 0, stream>>>(x, weff, b, y);
}